// Round 3
// baseline (258.203 us; speedup 1.0000x reference)
//
#include <hip/hip_runtime.h>

// CenterShift: out[n,o] = x[n] * (celu(celu((pos_j-pos_i)@w11+b11)@w12+b12) @ w13 + b13)[o]
// N = 2097152, dims 3 -> 16 -> 64 -> 64, fp32 in/out.
//
// Round 3:
//  - layer 2 AND layer 3 via mfma_f32_16x16x32_f16 (swapped operands: D[o,p]),
//    layer-2 K zero-padded 16->32; h1 computed directly in B-fragment layout.
//  - h2 tile in LDS, XOR-swizzled (byte ^= (pt&7)<<4): min-phase b64 writes /
//    b128 reads (verified bank arithmetic).
//  - output staged through LDS [16][68] f32 -> 4x contiguous 1KB store
//    instructions per 16 points (fill-kernel store pattern; kills the
//    scattered-64B-segment stores suspected of capping r2 at 3 TB/s).
//  - each wave processes 4 tiles of 64 points (amortizes fragment prologue).
// Per-wave LDS regions -> no __syncthreads anywhere; DS pipe is in-order per
// wave so buffer reuse across iterations is WAR-safe.

typedef __attribute__((ext_vector_type(8))) _Float16 f16x8;
typedef __attribute__((ext_vector_type(4))) float f32x4;

__device__ __forceinline__ float celu1(float a) {
    return a > 0.0f ? a : __expf(a) - 1.0f;
}

__global__ __launch_bounds__(256, 3) void centershift_kernel(
    const float* __restrict__ x,
    const float* __restrict__ pos_i,
    const float* __restrict__ pos_j,
    const float* __restrict__ w11, const float* __restrict__ b11,
    const float* __restrict__ w12, const float* __restrict__ b12,
    const float* __restrict__ w13, const float* __restrict__ b13,
    float* __restrict__ out, int n)
{
    __shared__ __align__(16) _Float16 h2s[4][64 * 64];  // 8 KB/wave, swizzled
    __shared__ __align__(16) float    oss[4][16 * 68];  // 4.25 KB/wave out-stage

    const int lane = threadIdx.x & 63;
    const int wid  = threadIdx.x >> 6;
    const int g    = lane >> 4;    // 16-lane group 0..3
    const int r16  = lane & 15;
    const int swz  = (r16 & 7) << 4;

    // ---- hoisted fragments (loop-invariant) ----
    // layer-3 A = w13^T: A[row=o_local=r16][k=kh*32+g*8+j]  (layout proven in r2)
    f16x8 a3[4][2];
#pragma unroll
    for (int u = 0; u < 4; ++u)
#pragma unroll
        for (int kh = 0; kh < 2; ++kh) {
            f16x8 v;
#pragma unroll
            for (int j = 0; j < 8; ++j)
                v[j] = (_Float16)w13[(kh * 32 + g * 8 + j) * 64 + u * 16 + r16];
            a3[u][kh] = v;
        }
    // layer-2 A = w12^T, K zero-padded 16->32 (k>=16 lanes supply 0)
    f16x8 a2[4];
#pragma unroll
    for (int u2 = 0; u2 < 4; ++u2) {
        f16x8 v;
#pragma unroll
        for (int j = 0; j < 8; ++j) {
            const int k = g * 8 + j;
            v[j] = (k < 16) ? (_Float16)w12[k * 64 + u2 * 16 + r16] : (_Float16)0.0f;
        }
        a2[u2] = v;
    }
    // biases in C/D layout: lane holds rows o = u*16 + g*4 + rr
    float b2v[4][4], b3v[4][4];
#pragma unroll
    for (int u = 0; u < 4; ++u)
#pragma unroll
        for (int rr = 0; rr < 4; ++rr) {
            b2v[u][rr] = b12[u * 16 + g * 4 + rr];
            b3v[u][rr] = b13[u * 16 + g * 4 + rr];
        }

    char*  h2b = (char*)&h2s[wid][0];
    float* os  = &oss[wid][0];

    const int wave_base = (blockIdx.x * 4 + wid) * 256;

#pragma unroll 1
    for (int tile = 0; tile < 4; ++tile) {
        const int tb = wave_base + tile * 64;
        if (tb >= n) break;

        // ---- layers 1+2: four 16-point column tiles ----
#pragma unroll
        for (int t = 0; t < 4; ++t) {
            const int pt = t * 16 + r16;
            const int q  = tb + pt;
            const float3 pi = *reinterpret_cast<const float3*>(pos_i + 3 * (size_t)q);
            const float3 pj = *reinterpret_cast<const float3*>(pos_j + 3 * (size_t)q);
            const float p0 = pj.x - pi.x, p1 = pj.y - pi.y, p2 = pj.z - pi.z;

            // h1 channels [ch0, ch0+8) of point q; B[k=g*8+j][col=r16]
            const int ch0 = (g & 1) * 8;
            f16x8 b2f;
#pragma unroll
            for (int j = 0; j < 8; ++j) {
                const int c = ch0 + j;
                float a = b11[c];
                a = fmaf(p0, w11[c], a);
                a = fmaf(p1, w11[16 + c], a);
                a = fmaf(p2, w11[32 + c], a);
                a = celu1(a);
                b2f[j] = (g < 2) ? (_Float16)a : (_Float16)0.0f;
            }
#pragma unroll
            for (int u2 = 0; u2 < 4; ++u2) {
                f32x4 acc = { b2v[u2][0], b2v[u2][1], b2v[u2][2], b2v[u2][3] };
                acc = __builtin_amdgcn_mfma_f32_16x16x32_f16(a2[u2], b2f, acc, 0, 0, 0);
                union { _Float16 h[4]; unsigned long long v; } pk;
                pk.h[0] = (_Float16)celu1(acc[0]);
                pk.h[1] = (_Float16)celu1(acc[1]);
                pk.h[2] = (_Float16)celu1(acc[2]);
                pk.h[3] = (_Float16)celu1(acc[3]);
                // h2[pt][ch = u2*16 + g*4 + 0..3], byte = pt*128 + ch*2, swizzled
                const int byteoff = pt * 128 + u2 * 32 + g * 8;
                *reinterpret_cast<unsigned long long*>(h2b + (byteoff ^ swz)) = pk.v;
            }
        }

        // ---- layer 3 + staged contiguous stores ----
#pragma unroll
        for (int t2 = 0; t2 < 4; ++t2) {
            const int pt = t2 * 16 + r16;
            const f16x8 bb0 = *reinterpret_cast<const f16x8*>(h2b + ((pt * 128 +      g * 16) ^ swz));
            const f16x8 bb1 = *reinterpret_cast<const f16x8*>(h2b + ((pt * 128 + 64 + g * 16) ^ swz));
            const float xvt = x[tb + pt];
#pragma unroll
            for (int u = 0; u < 4; ++u) {
                f32x4 acc = { b3v[u][0], b3v[u][1], b3v[u][2], b3v[u][3] };
                acc = __builtin_amdgcn_mfma_f32_16x16x32_f16(a3[u][0], bb0, acc, 0, 0, 0);
                acc = __builtin_amdgcn_mfma_f32_16x16x32_f16(a3[u][1], bb1, acc, 0, 0, 0);
                float4 o4 = { acc[0] * xvt, acc[1] * xvt, acc[2] * xvt, acc[3] * xvt };
                // stage [point r16][ch u*16+g*4 .. +4), stride 68 (conflict-free)
                *reinterpret_cast<float4*>(os + r16 * 68 + u * 16 + g * 4) = o4;
            }
            // stream 16 points x 256 B = 4 KB as 4 contiguous 1KB instructions
            float* og = out + (size_t)(tb + t2 * 16) * 64;
#pragma unroll
            for (int it = 0; it < 4; ++it) {
                const int idx = it * 256 + lane * 4;
                const int pp = idx >> 6, cc = idx & 63;
                const float4 v = *reinterpret_cast<const float4*>(os + pp * 68 + cc);
                *reinterpret_cast<float4*>(og + idx) = v;
            }
        }
    }
}

extern "C" void kernel_launch(void* const* d_in, const int* in_sizes, int n_in,
                              void* d_out, int out_size, void* d_ws, size_t ws_size,
                              hipStream_t stream) {
    const float* x     = (const float*)d_in[0];
    const float* pos_i = (const float*)d_in[1];
    const float* pos_j = (const float*)d_in[2];
    const float* w11   = (const float*)d_in[3];
    const float* b11   = (const float*)d_in[4];
    const float* w12   = (const float*)d_in[5];
    const float* b12   = (const float*)d_in[6];
    const float* w13   = (const float*)d_in[7];
    const float* b13   = (const float*)d_in[8];
    float* out = (float*)d_out;

    const int n = in_sizes[0];                   // N (x is [N,1])
    const int blocks = (n + 1023) / 1024;        // 4 waves x 4 tiles x 64 points
    centershift_kernel<<<blocks, 256, 0, stream>>>(
        x, pos_i, pos_j, w11, b11, w12, b12, w13, b13, out, n);
}